// Round 7
// baseline (79.029 us; speedup 1.0000x reference)
//
#include <hip/hip_runtime.h>

#define BATCH 256
#define IN1   10240
#define NU    32
#define SPLITS 256
#define STRIPE (IN1 / SPLITS)   // 40
#define SUB   8                 // i's per inner step
#define NSUB  (STRIPE / SUB)    // 5
#define LOG2E 1.4426950408889634f

// ---------------- Kernel 0: pack transformed params -----------------------
// Ppack layout: [uq][i][uj] float4 {A, C, W, W*erev}, uq = u>>3, uj = u&7.
__global__ __launch_bounds__(256) void ltc_pack(
    const float* __restrict__ iw, const float* __restrict__ ibias,
    const float* __restrict__ smu, const float* __restrict__ ssig,
    const float* __restrict__ sW, const float* __restrict__ serev,
    float4* __restrict__ Ppack)
{
    const int idx = blockIdx.x * 256 + threadIdx.x;   // 0..IN1*NU-1
    const int i = idx >> 5;
    const int u = idx & 31;
    const float sg = ssig[idx] * LOG2E;
    const float A  = sg * iw[i];
    const float C  = (smu[idx] - ibias[i]) * sg;
    const float w  = sW[idx];
    const int uq = u >> 3, uj = u & 7;
    Ppack[((size_t)uq * IN1 + i) * 8 + uj] =
        make_float4(A, C, w, w * serev[idx]);
}

// ---------------- Kernel 1: sensory partial sums --------------------------
// grid = (4 u-quarters, SPLITS stripes); block = 256 threads = 256 batches
// (lane = batch). Param base pointer is laundered through inline asm so the
// compiler CANNOT scalarize it: loads go to the in-order VMEM pipe
// (global_load_dwordx4 + imm offsets) and get software-pipelined with
// partial vmcnt waits, instead of s_load + lgkmcnt(0) full drains.
__global__ __launch_bounds__(256) void ltc_sensory_partial(
    const float* __restrict__ x,
    const float4* __restrict__ Ppack,
    float4* __restrict__ part)
{
    const int b  = threadIdx.x;          // batch (lane)
    const int uq = blockIdx.x;           // 0..3
    const int s  = blockIdx.y;           // 0..SPLITS-1
    const int i0 = s * STRIPE;

    float accn[8], accd[8];
#pragma unroll
    for (int k = 0; k < 8; ++k) { accn[k] = 0.f; accd[k] = 0.f; }

    const float* xrow = x + (size_t)b * IN1 + i0;

    // launder: force the (block-uniform) param pointer into VGPRs
    const char* pb = (const char*)(Ppack + ((size_t)uq * IN1 + i0) * 8);
    asm("" : "+v"(pb));

    for (int sc = 0; sc < NSUB; ++sc) {
        union { float4 v4[2]; float f[8]; } xu;
        xu.v4[0] = *(const float4*)(xrow + sc * SUB);
        xu.v4[1] = *(const float4*)(xrow + sc * SUB + 4);

        const float4* pp = (const float4*)(pb + (size_t)sc * (SUB * 8 * 16));
#pragma unroll
        for (int di = 0; di < SUB; ++di) {
            const float xv = xu.f[di];
#pragma unroll
            for (int uj = 0; uj < 8; ++uj) {
                const float4 f = pp[di * 8 + uj];      // imm offset 0..1008
                const float e = __builtin_amdgcn_exp2f(f.y - xv * f.x);
                const float r = __builtin_amdgcn_rcpf(1.0f + e);
                accd[uj] = fmaf(f.z, r, accd[uj]);
                accn[uj] = fmaf(f.w, r, accn[uj]);
            }
        }
    }

    // lane writes its own 64B line: 4x float4 {n,d,n,d,...}
    float4* po = part + (((size_t)s * BATCH + b) * NU + uq * 8) / 2;
#pragma unroll
    for (int q = 0; q < 4; ++q)
        po[q] = make_float4(accn[2*q], accd[2*q], accn[2*q+1], accd[2*q+1]);
}

// ---------------- Kernel 2: reduce split partials -------------------------
__global__ __launch_bounds__(256) void ltc_reduce(
    const float2* __restrict__ part, int nsplit, float2* __restrict__ S)
{
    const int tid = threadIdx.x;
    const int b   = blockIdx.x;
    const int u   = tid & 31;
    const int sl  = tid >> 5;

    __shared__ float sred[8][NU][2];

    float sn = 0.f, sd = 0.f;
#pragma unroll 8
    for (int s = sl; s < nsplit; s += 8) {
        const float2 p = part[((size_t)s * BATCH + b) * NU + u];
        sn += p.x;
        sd += p.y;
    }
    sred[sl][u][0] = sn;
    sred[sl][u][1] = sd;
    __syncthreads();

    if (tid >= 32) return;
    float Sn = 0.f, Sd = 0.f;
#pragma unroll
    for (int s2 = 0; s2 < 8; ++s2) {
        Sn += sred[s2][u][0];
        Sd += sred[s2][u][1];
    }
    S[(size_t)b * NU + u] = make_float2(Sn, Sd);
}

// ---------------- Kernel 3: unfolds + cell B + output ---------------------
__global__ __launch_bounds__(256) void ltc_unfold(
    const float2* __restrict__ S,
    const float* __restrict__ amu, const float* __restrict__ asig,
    const float* __restrict__ aW,  const float* __restrict__ aerev,
    const float* __restrict__ agleak, const float* __restrict__ avleak,
    const float* __restrict__ acm,
    const float* __restrict__ b_iw, const float* __restrict__ b_ib,
    const float* __restrict__ b_smu, const float* __restrict__ b_ssig,
    const float* __restrict__ b_sW,  const float* __restrict__ b_serev,
    const float* __restrict__ b_mu,  const float* __restrict__ b_sig,
    const float* __restrict__ b_W,   const float* __restrict__ b_erev,
    const float* __restrict__ b_gleak, const float* __restrict__ b_vleak,
    const float* __restrict__ b_cm,
    float* __restrict__ out)
{
    const int tid = threadIdx.x;
    const int u   = tid & 31;
    const int bl  = tid >> 5;
    const int b   = blockIdx.x * 8 + bl;

    __shared__ float pAp[NU*NU], pCp[NU*NU];
    __shared__ float pW[NU*NU],  pWE[NU*NU];

    for (int p = tid; p < NU * NU; p += 256) {
        const float sg = asig[p] * LOG2E;
        pAp[p] = sg;
        pCp[p] = amu[p] * sg;
        const float w = aW[p];
        pW[p]  = w;
        pWE[p] = w * aerev[p];
    }
    __syncthreads();

    const float2 Sv = S[(size_t)b * NU + u];
    const float Sn = Sv.x, Sd = Sv.y;

    const float cmt = acm[u] * 6.0f;
    const float gl  = agleak[u];
    const float gv  = gl * avleak[u];

    float v = 0.f;
    for (int k = 0; k < 6; ++k) {
        float rn = 0.f, rd = 0.f;
#pragma unroll
        for (int j = 0; j < NU; ++j) {
            const float vj = __shfl(v, j, 32);
            const int pi = j * NU + u;
            const float e = __builtin_amdgcn_exp2f(pCp[pi] - vj * pAp[pi]);
            const float r = __builtin_amdgcn_rcpf(1.0f + e);
            rn = fmaf(pWE[pi], r, rn);
            rd = fmaf(pW[pi],  r, rd);
        }
        const float num = cmt * v + gv + rn + Sn;
        const float den = cmt + gl + rd + Sd;
        v = num / den;
    }

    const float x2  = v * b_iw[u] + b_ib[u];
    const float e2  = __builtin_amdgcn_exp2f((b_smu[u] - x2) * b_ssig[u] * LOG2E);
    const float s2v = b_sW[u] * __builtin_amdgcn_rcpf(1.0f + e2);
    float wn = s2v * b_serev[u];
    float wd = s2v;
#pragma unroll
    for (int m = 16; m >= 1; m >>= 1) {
        wn += __shfl_xor(wn, m, 32);
        wd += __shfl_xor(wd, m, 32);
    }

    const float bcmt = b_cm[0] * 6.0f;
    const float bgl  = b_gleak[0];
    const float bgv  = bgl * b_vleak[0];
    const float bmu  = b_mu[0], bsig = b_sig[0], bW = b_W[0], berev = b_erev[0];
    float v2 = 0.f;
#pragma unroll
    for (int k = 0; k < 6; ++k) {
        const float ee = __builtin_amdgcn_exp2f((bmu - v2) * bsig * LOG2E);
        const float ws = bW * __builtin_amdgcn_rcpf(1.0f + ee);
        const float num = bcmt * v2 + bgv + ws * berev + wn;
        const float den = bcmt + bgl + ws + wd;
        v2 = num / den;
    }

    if (u == 0)
        out[b] = 1.0f / (1.0f + __builtin_amdgcn_exp2f(-v2 * LOG2E));
}

extern "C" void kernel_launch(void* const* d_in, const int* in_sizes, int n_in,
                              void* d_out, int out_size, void* d_ws, size_t ws_size,
                              hipStream_t stream) {
    const float* x       = (const float*)d_in[0];
    const float* a_iw    = (const float*)d_in[1];
    const float* a_ib    = (const float*)d_in[2];
    const float* a_smu   = (const float*)d_in[3];
    const float* a_ssig  = (const float*)d_in[4];
    const float* a_sW    = (const float*)d_in[5];
    const float* a_serev = (const float*)d_in[6];
    const float* a_mu    = (const float*)d_in[7];
    const float* a_sig   = (const float*)d_in[8];
    const float* a_W     = (const float*)d_in[9];
    const float* a_erev  = (const float*)d_in[10];
    const float* a_gleak = (const float*)d_in[11];
    const float* a_vleak = (const float*)d_in[12];
    const float* a_cm    = (const float*)d_in[13];
    const float* b_iw    = (const float*)d_in[14];
    const float* b_ib    = (const float*)d_in[15];
    const float* b_smu   = (const float*)d_in[16];
    const float* b_ssig  = (const float*)d_in[17];
    const float* b_sW    = (const float*)d_in[18];
    const float* b_serev = (const float*)d_in[19];
    const float* b_mu    = (const float*)d_in[20];
    const float* b_sig   = (const float*)d_in[21];
    const float* b_W     = (const float*)d_in[22];
    const float* b_erev  = (const float*)d_in[23];
    const float* b_gleak = (const float*)d_in[24];
    const float* b_vleak = (const float*)d_in[25];
    const float* b_cm    = (const float*)d_in[26];
    float* out = (float*)d_out;

    float4* Ppack = (float4*)d_ws;                               // 5.24 MB
    float4* part  = Ppack + (size_t)IN1 * NU;                    // 16.8 MB
    float2* Sarr  = (float2*)(part + (size_t)SPLITS * BATCH * NU / 2);

    ltc_pack<<<(IN1 * NU) / 256, 256, 0, stream>>>(
        a_iw, a_ib, a_smu, a_ssig, a_sW, a_serev, Ppack);

    dim3 g1(4, SPLITS);
    ltc_sensory_partial<<<g1, 256, 0, stream>>>(x, Ppack, part);

    ltc_reduce<<<BATCH, 256, 0, stream>>>((const float2*)part, SPLITS, Sarr);

    ltc_unfold<<<BATCH / 8, 256, 0, stream>>>(
        Sarr,
        a_mu, a_sig, a_W, a_erev, a_gleak, a_vleak, a_cm,
        b_iw, b_ib, b_smu, b_ssig, b_sW, b_serev,
        b_mu, b_sig, b_W, b_erev, b_gleak, b_vleak, b_cm,
        out);
}

// Round 8
// 55.134 us; speedup vs baseline: 1.4334x; 1.4334x over previous
//
#include <hip/hip_runtime.h>

#define BATCH 256
#define IN1   10240
#define NU    32
#define SPLITS 128
#define STRIPE (IN1 / SPLITS)   // 80 i per block
#define BBLK  16                // b per block (4 per wave)
#define LOG2E 1.4426950408889634f

// ---------------- Kernel 0: pack transformed params -----------------------
// Ppk[i*32+u] = {A, C, W, W*erev};  A = iw*ssig*log2e, C = (smu-ib)*ssig*log2e
__global__ __launch_bounds__(256) void ltc_pack(
    const float* __restrict__ iw, const float* __restrict__ ibias,
    const float* __restrict__ smu, const float* __restrict__ ssig,
    const float* __restrict__ sW, const float* __restrict__ serev,
    float4* __restrict__ Ppk)
{
    const int idx = blockIdx.x * 256 + threadIdx.x;   // 0..IN1*NU-1
    const int i = idx >> 5;
    const float sg = ssig[idx] * LOG2E;
    const float A  = sg * iw[i];
    const float C  = (smu[idx] - ibias[i]) * sg;
    const float w  = sW[idx];
    Ppk[idx] = make_float4(A, C, w, w * serev[idx]);
}

// ---------------- Kernel 1: sensory partial sums --------------------------
// grid = (16 b-tiles, 128 i-stripes), block = 256. lane = (il = (tid>>5)&1,
// u = tid&31); wave wv owns b = bt*16 + wv*4 + {0..3}; thread owns rows
// bA = ..+il and bB = ..+2+il. Param loads are per-lane coalesced dwordx4
// (1 instr serves 64 tasks); x loads are float4 over i. Thread owns its
// (b,u) outputs fully -> no reduction, coalesced float2 stores.
__global__ __launch_bounds__(256, 4) void ltc_sensory_partial(
    const float* __restrict__ x,
    const float4* __restrict__ Ppk,
    float2* __restrict__ part)
{
    const int tid = threadIdx.x;
    const int u   = tid & 31;
    const int il  = (tid >> 5) & 1;
    const int wv  = tid >> 6;
    const int bt  = blockIdx.x;          // 0..15
    const int s   = blockIdx.y;          // 0..SPLITS-1
    const int i0  = s * STRIPE;
    const int bA  = bt * BBLK + wv * 4 + il;
    const int bB  = bA + 2;

    const float*  xrA = x + (size_t)bA * IN1 + i0;
    const float*  xrB = x + (size_t)bB * IN1 + i0;
    const float4* pb  = Ppk + (size_t)i0 * NU + u;

    float anA = 0.f, adA = 0.f, anB = 0.f, adB = 0.f;

#pragma unroll 2
    for (int k4 = 0; k4 < STRIPE / 4; ++k4) {
        const float4 xa = *(const float4*)(xrA + k4 * 4);
        const float4 xb = *(const float4*)(xrB + k4 * 4);
        const float xaf[4] = {xa.x, xa.y, xa.z, xa.w};
        const float xbf[4] = {xb.x, xb.y, xb.z, xb.w};
#pragma unroll
        for (int t = 0; t < 4; ++t) {
            const float4 p = pb[(size_t)(k4 * 4 + t) * NU];
            {
                const float e = __builtin_amdgcn_exp2f(p.y - xaf[t] * p.x);
                const float r = __builtin_amdgcn_rcpf(1.0f + e);
                adA = fmaf(p.z, r, adA);
                anA = fmaf(p.w, r, anA);
            }
            {
                const float e = __builtin_amdgcn_exp2f(p.y - xbf[t] * p.x);
                const float r = __builtin_amdgcn_rcpf(1.0f + e);
                adB = fmaf(p.z, r, adB);
                anB = fmaf(p.w, r, anB);
            }
        }
    }

    float2* po = part + (size_t)s * BATCH * NU;
    po[(size_t)bA * NU + u] = make_float2(anA, adA);
    po[(size_t)bB * NU + u] = make_float2(anB, adB);
}

// ---------------- Kernel 2: reduce split partials -------------------------
__global__ __launch_bounds__(256) void ltc_reduce(
    const float2* __restrict__ part, int nsplit, float2* __restrict__ S)
{
    const int tid = threadIdx.x;
    const int b   = blockIdx.x;
    const int u   = tid & 31;
    const int sl  = tid >> 5;

    __shared__ float sred[8][NU][2];

    float sn = 0.f, sd = 0.f;
#pragma unroll 8
    for (int s = sl; s < nsplit; s += 8) {
        const float2 p = part[((size_t)s * BATCH + b) * NU + u];
        sn += p.x;
        sd += p.y;
    }
    sred[sl][u][0] = sn;
    sred[sl][u][1] = sd;
    __syncthreads();

    if (tid >= 32) return;
    float Sn = 0.f, Sd = 0.f;
#pragma unroll
    for (int s2 = 0; s2 < 8; ++s2) {
        Sn += sred[s2][u][0];
        Sd += sred[s2][u][1];
    }
    S[(size_t)b * NU + u] = make_float2(Sn, Sd);
}

// ---------------- Kernel 3: unfolds + cell B + output ---------------------
__global__ __launch_bounds__(256) void ltc_unfold(
    const float2* __restrict__ S,
    const float* __restrict__ amu, const float* __restrict__ asig,
    const float* __restrict__ aW,  const float* __restrict__ aerev,
    const float* __restrict__ agleak, const float* __restrict__ avleak,
    const float* __restrict__ acm,
    const float* __restrict__ b_iw, const float* __restrict__ b_ib,
    const float* __restrict__ b_smu, const float* __restrict__ b_ssig,
    const float* __restrict__ b_sW,  const float* __restrict__ b_serev,
    const float* __restrict__ b_mu,  const float* __restrict__ b_sig,
    const float* __restrict__ b_W,   const float* __restrict__ b_erev,
    const float* __restrict__ b_gleak, const float* __restrict__ b_vleak,
    const float* __restrict__ b_cm,
    float* __restrict__ out)
{
    const int tid = threadIdx.x;
    const int u   = tid & 31;
    const int bl  = tid >> 5;
    const int b   = blockIdx.x * 8 + bl;

    __shared__ float pAp[NU*NU], pCp[NU*NU];
    __shared__ float pW[NU*NU],  pWE[NU*NU];

    for (int p = tid; p < NU * NU; p += 256) {
        const float sg = asig[p] * LOG2E;
        pAp[p] = sg;
        pCp[p] = amu[p] * sg;
        const float w = aW[p];
        pW[p]  = w;
        pWE[p] = w * aerev[p];
    }
    __syncthreads();

    const float2 Sv = S[(size_t)b * NU + u];
    const float Sn = Sv.x, Sd = Sv.y;

    const float cmt = acm[u] * 6.0f;
    const float gl  = agleak[u];
    const float gv  = gl * avleak[u];

    float v = 0.f;
    for (int k = 0; k < 6; ++k) {
        float rn = 0.f, rd = 0.f;
#pragma unroll
        for (int j = 0; j < NU; ++j) {
            const float vj = __shfl(v, j, 32);
            const int pi = j * NU + u;
            const float e = __builtin_amdgcn_exp2f(pCp[pi] - vj * pAp[pi]);
            const float r = __builtin_amdgcn_rcpf(1.0f + e);
            rn = fmaf(pWE[pi], r, rn);
            rd = fmaf(pW[pi],  r, rd);
        }
        const float num = cmt * v + gv + rn + Sn;
        const float den = cmt + gl + rd + Sd;
        v = num / den;
    }

    const float x2  = v * b_iw[u] + b_ib[u];
    const float e2  = __builtin_amdgcn_exp2f((b_smu[u] - x2) * b_ssig[u] * LOG2E);
    const float s2v = b_sW[u] * __builtin_amdgcn_rcpf(1.0f + e2);
    float wn = s2v * b_serev[u];
    float wd = s2v;
#pragma unroll
    for (int m = 16; m >= 1; m >>= 1) {
        wn += __shfl_xor(wn, m, 32);
        wd += __shfl_xor(wd, m, 32);
    }

    const float bcmt = b_cm[0] * 6.0f;
    const float bgl  = b_gleak[0];
    const float bgv  = bgl * b_vleak[0];
    const float bmu  = b_mu[0], bsig = b_sig[0], bW = b_W[0], berev = b_erev[0];
    float v2 = 0.f;
#pragma unroll
    for (int k = 0; k < 6; ++k) {
        const float ee = __builtin_amdgcn_exp2f((bmu - v2) * bsig * LOG2E);
        const float ws = bW * __builtin_amdgcn_rcpf(1.0f + ee);
        const float num = bcmt * v2 + bgv + ws * berev + wn;
        const float den = bcmt + bgl + ws + wd;
        v2 = num / den;
    }

    if (u == 0)
        out[b] = 1.0f / (1.0f + __builtin_amdgcn_exp2f(-v2 * LOG2E));
}

extern "C" void kernel_launch(void* const* d_in, const int* in_sizes, int n_in,
                              void* d_out, int out_size, void* d_ws, size_t ws_size,
                              hipStream_t stream) {
    const float* x       = (const float*)d_in[0];
    const float* a_iw    = (const float*)d_in[1];
    const float* a_ib    = (const float*)d_in[2];
    const float* a_smu   = (const float*)d_in[3];
    const float* a_ssig  = (const float*)d_in[4];
    const float* a_sW    = (const float*)d_in[5];
    const float* a_serev = (const float*)d_in[6];
    const float* a_mu    = (const float*)d_in[7];
    const float* a_sig   = (const float*)d_in[8];
    const float* a_W     = (const float*)d_in[9];
    const float* a_erev  = (const float*)d_in[10];
    const float* a_gleak = (const float*)d_in[11];
    const float* a_vleak = (const float*)d_in[12];
    const float* a_cm    = (const float*)d_in[13];
    const float* b_iw    = (const float*)d_in[14];
    const float* b_ib    = (const float*)d_in[15];
    const float* b_smu   = (const float*)d_in[16];
    const float* b_ssig  = (const float*)d_in[17];
    const float* b_sW    = (const float*)d_in[18];
    const float* b_serev = (const float*)d_in[19];
    const float* b_mu    = (const float*)d_in[20];
    const float* b_sig   = (const float*)d_in[21];
    const float* b_W     = (const float*)d_in[22];
    const float* b_erev  = (const float*)d_in[23];
    const float* b_gleak = (const float*)d_in[24];
    const float* b_vleak = (const float*)d_in[25];
    const float* b_cm    = (const float*)d_in[26];
    float* out = (float*)d_out;

    float4* Ppk  = (float4*)d_ws;                                // 5.24 MB
    float2* part = (float2*)(Ppk + (size_t)IN1 * NU);            // 8.39 MB
    float2* Sarr = part + (size_t)SPLITS * BATCH * NU;           // 16 KB

    ltc_pack<<<(IN1 * NU) / 256, 256, 0, stream>>>(
        a_iw, a_ib, a_smu, a_ssig, a_sW, a_serev, Ppk);

    dim3 g1(BATCH / BBLK, SPLITS);
    ltc_sensory_partial<<<g1, 256, 0, stream>>>(x, Ppk, part);

    ltc_reduce<<<BATCH, 256, 0, stream>>>(part, SPLITS, Sarr);

    ltc_unfold<<<BATCH / 8, 256, 0, stream>>>(
        Sarr,
        a_mu, a_sig, a_W, a_erev, a_gleak, a_vleak, a_cm,
        b_iw, b_ib, b_smu, b_ssig, b_sW, b_serev,
        b_mu, b_sig, b_W, b_erev, b_gleak, b_vleak, b_cm,
        out);
}

// Round 9
// 49.561 us; speedup vs baseline: 1.5946x; 1.1124x over previous
//
#include <hip/hip_runtime.h>

#define BATCH 256
#define IN1   10240
#define NU    32
#define SPLITS 128
#define STRIPE (IN1 / SPLITS)   // 80 i per block
#define BBLK  32                // b per block (8 per wave, 4 per thread)
#define NGRP  (STRIPE / 4)      // 20 groups of 4 i
#define LOG2E 1.4426950408889634f

// ---------------- Kernel 0: pack transformed params -----------------------
// Ppk[i*32+u] = {A, C, W, W*erev};  A = iw*ssig*log2e, C = (smu-ib)*ssig*log2e
__global__ __launch_bounds__(256) void ltc_pack(
    const float* __restrict__ iw, const float* __restrict__ ibias,
    const float* __restrict__ smu, const float* __restrict__ ssig,
    const float* __restrict__ sW, const float* __restrict__ serev,
    float4* __restrict__ Ppk)
{
    const int idx = blockIdx.x * 256 + threadIdx.x;   // 0..IN1*NU-1
    const int i = idx >> 5;
    const float sg = ssig[idx] * LOG2E;
    const float A  = sg * iw[i];
    const float C  = (smu[idx] - ibias[i]) * sg;
    const float w  = sW[idx];
    Ppk[idx] = make_float4(A, C, w, w * serev[idx]);
}

// ---------------- Kernel 1: sensory partial sums --------------------------
// grid = (8 b-tiles, 128 i-stripes), block = 256. lane = (il=(tid>>5)&1,
// u=tid&31); thread owns 4 batches b0..b0+3. Params per-lane coalesced
// dwordx4 (512B/instr); x per-thread float4. Manual 2-stage software
// pipeline with NAMED register buffers so group g+1's 8 VMEM loads are in
// flight while group g computes (partial vmcnt waits, not load-use stalls).
#define LOAD_GRP(p0,p1,p2,p3,x0,x1,x2,x3,g) do {                          \
    const float4* _pp = pb + (size_t)(g) * 4 * NU;                        \
    p0 = _pp[0];  p1 = _pp[NU];  p2 = _pp[2*NU];  p3 = _pp[3*NU];         \
    const int _o = (g) * 4;                                               \
    x0 = *(const float4*)(xr0 + _o);                                      \
    x1 = *(const float4*)(xr1 + _o);                                      \
    x2 = *(const float4*)(xr2 + _o);                                      \
    x3 = *(const float4*)(xr3 + _o);                                      \
} while (0)

#define SIG4(p, v0, v1, v2, v3) do {                                      \
    float e, r;                                                           \
    e = __builtin_amdgcn_exp2f(p.y - (v0) * p.x);                         \
    r = __builtin_amdgcn_rcpf(1.0f + e);                                  \
    ad0 = fmaf(p.z, r, ad0); an0 = fmaf(p.w, r, an0);                     \
    e = __builtin_amdgcn_exp2f(p.y - (v1) * p.x);                         \
    r = __builtin_amdgcn_rcpf(1.0f + e);                                  \
    ad1 = fmaf(p.z, r, ad1); an1 = fmaf(p.w, r, an1);                     \
    e = __builtin_amdgcn_exp2f(p.y - (v2) * p.x);                         \
    r = __builtin_amdgcn_rcpf(1.0f + e);                                  \
    ad2 = fmaf(p.z, r, ad2); an2 = fmaf(p.w, r, an2);                     \
    e = __builtin_amdgcn_exp2f(p.y - (v3) * p.x);                         \
    r = __builtin_amdgcn_rcpf(1.0f + e);                                  \
    ad3 = fmaf(p.z, r, ad3); an3 = fmaf(p.w, r, an3);                     \
} while (0)

#define COMP_GRP(p0,p1,p2,p3,x0,x1,x2,x3) do {                            \
    SIG4(p0, x0.x, x1.x, x2.x, x3.x);                                     \
    SIG4(p1, x0.y, x1.y, x2.y, x3.y);                                     \
    SIG4(p2, x0.z, x1.z, x2.z, x3.z);                                     \
    SIG4(p3, x0.w, x1.w, x2.w, x3.w);                                     \
} while (0)

__global__ __launch_bounds__(256, 4) void ltc_sensory_partial(
    const float* __restrict__ x,
    const float4* __restrict__ Ppk,
    float2* __restrict__ part)
{
    const int tid = threadIdx.x;
    const int u   = tid & 31;
    const int il  = (tid >> 5) & 1;
    const int wv  = tid >> 6;
    const int bt  = blockIdx.x;          // 0..7
    const int s   = blockIdx.y;          // 0..SPLITS-1
    const int i0  = s * STRIPE;
    const int b0  = bt * BBLK + wv * 8 + il * 4;

    const float* xr0 = x + (size_t)(b0 + 0) * IN1 + i0;
    const float* xr1 = x + (size_t)(b0 + 1) * IN1 + i0;
    const float* xr2 = x + (size_t)(b0 + 2) * IN1 + i0;
    const float* xr3 = x + (size_t)(b0 + 3) * IN1 + i0;
    const float4* pb = Ppk + (size_t)i0 * NU + u;

    float an0 = 0.f, ad0 = 0.f, an1 = 0.f, ad1 = 0.f;
    float an2 = 0.f, ad2 = 0.f, an3 = 0.f, ad3 = 0.f;

    float4 pA0, pA1, pA2, pA3, xA0, xA1, xA2, xA3;   // buffer A
    float4 pB0, pB1, pB2, pB3, xB0, xB1, xB2, xB3;   // buffer B

    LOAD_GRP(pA0,pA1,pA2,pA3, xA0,xA1,xA2,xA3, 0);
#pragma unroll 1
    for (int g = 0; g < NGRP - 2; g += 2) {
        LOAD_GRP(pB0,pB1,pB2,pB3, xB0,xB1,xB2,xB3, g + 1);
        COMP_GRP(pA0,pA1,pA2,pA3, xA0,xA1,xA2,xA3);
        LOAD_GRP(pA0,pA1,pA2,pA3, xA0,xA1,xA2,xA3, g + 2);
        COMP_GRP(pB0,pB1,pB2,pB3, xB0,xB1,xB2,xB3);
    }
    LOAD_GRP(pB0,pB1,pB2,pB3, xB0,xB1,xB2,xB3, NGRP - 1);
    COMP_GRP(pA0,pA1,pA2,pA3, xA0,xA1,xA2,xA3);
    COMP_GRP(pB0,pB1,pB2,pB3, xB0,xB1,xB2,xB3);

    float2* po = part + (size_t)s * BATCH * NU;
    po[(size_t)(b0 + 0) * NU + u] = make_float2(an0, ad0);
    po[(size_t)(b0 + 1) * NU + u] = make_float2(an1, ad1);
    po[(size_t)(b0 + 2) * NU + u] = make_float2(an2, ad2);
    po[(size_t)(b0 + 3) * NU + u] = make_float2(an3, ad3);
}

// ---------------- Kernel 2: reduce split partials -------------------------
__global__ __launch_bounds__(256) void ltc_reduce(
    const float2* __restrict__ part, int nsplit, float2* __restrict__ S)
{
    const int tid = threadIdx.x;
    const int b   = blockIdx.x;
    const int u   = tid & 31;
    const int sl  = tid >> 5;

    __shared__ float sred[8][NU][2];

    float sn = 0.f, sd = 0.f;
#pragma unroll 8
    for (int s = sl; s < nsplit; s += 8) {
        const float2 p = part[((size_t)s * BATCH + b) * NU + u];
        sn += p.x;
        sd += p.y;
    }
    sred[sl][u][0] = sn;
    sred[sl][u][1] = sd;
    __syncthreads();

    if (tid >= 32) return;
    float Sn = 0.f, Sd = 0.f;
#pragma unroll
    for (int s2 = 0; s2 < 8; ++s2) {
        Sn += sred[s2][u][0];
        Sd += sred[s2][u][1];
    }
    S[(size_t)b * NU + u] = make_float2(Sn, Sd);
}

// ---------------- Kernel 3: unfolds + cell B + output ---------------------
__global__ __launch_bounds__(256) void ltc_unfold(
    const float2* __restrict__ S,
    const float* __restrict__ amu, const float* __restrict__ asig,
    const float* __restrict__ aW,  const float* __restrict__ aerev,
    const float* __restrict__ agleak, const float* __restrict__ avleak,
    const float* __restrict__ acm,
    const float* __restrict__ b_iw, const float* __restrict__ b_ib,
    const float* __restrict__ b_smu, const float* __restrict__ b_ssig,
    const float* __restrict__ b_sW,  const float* __restrict__ b_serev,
    const float* __restrict__ b_mu,  const float* __restrict__ b_sig,
    const float* __restrict__ b_W,   const float* __restrict__ b_erev,
    const float* __restrict__ b_gleak, const float* __restrict__ b_vleak,
    const float* __restrict__ b_cm,
    float* __restrict__ out)
{
    const int tid = threadIdx.x;
    const int u   = tid & 31;
    const int bl  = tid >> 5;
    const int b   = blockIdx.x * 8 + bl;

    __shared__ float pAp[NU*NU], pCp[NU*NU];
    __shared__ float pW[NU*NU],  pWE[NU*NU];

    for (int p = tid; p < NU * NU; p += 256) {
        const float sg = asig[p] * LOG2E;
        pAp[p] = sg;
        pCp[p] = amu[p] * sg;
        const float w = aW[p];
        pW[p]  = w;
        pWE[p] = w * aerev[p];
    }
    __syncthreads();

    const float2 Sv = S[(size_t)b * NU + u];
    const float Sn = Sv.x, Sd = Sv.y;

    const float cmt = acm[u] * 6.0f;
    const float gl  = agleak[u];
    const float gv  = gl * avleak[u];

    float v = 0.f;
    for (int k = 0; k < 6; ++k) {
        float rn = 0.f, rd = 0.f;
#pragma unroll
        for (int j = 0; j < NU; ++j) {
            const float vj = __shfl(v, j, 32);
            const int pi = j * NU + u;
            const float e = __builtin_amdgcn_exp2f(pCp[pi] - vj * pAp[pi]);
            const float r = __builtin_amdgcn_rcpf(1.0f + e);
            rn = fmaf(pWE[pi], r, rn);
            rd = fmaf(pW[pi],  r, rd);
        }
        const float num = cmt * v + gv + rn + Sn;
        const float den = cmt + gl + rd + Sd;
        v = num / den;
    }

    const float x2  = v * b_iw[u] + b_ib[u];
    const float e2  = __builtin_amdgcn_exp2f((b_smu[u] - x2) * b_ssig[u] * LOG2E);
    const float s2v = b_sW[u] * __builtin_amdgcn_rcpf(1.0f + e2);
    float wn = s2v * b_serev[u];
    float wd = s2v;
#pragma unroll
    for (int m = 16; m >= 1; m >>= 1) {
        wn += __shfl_xor(wn, m, 32);
        wd += __shfl_xor(wd, m, 32);
    }

    const float bcmt = b_cm[0] * 6.0f;
    const float bgl  = b_gleak[0];
    const float bgv  = bgl * b_vleak[0];
    const float bmu  = b_mu[0], bsig = b_sig[0], bW = b_W[0], berev = b_erev[0];
    float v2 = 0.f;
#pragma unroll
    for (int k = 0; k < 6; ++k) {
        const float ee = __builtin_amdgcn_exp2f((bmu - v2) * bsig * LOG2E);
        const float ws = bW * __builtin_amdgcn_rcpf(1.0f + ee);
        const float num = bcmt * v2 + bgv + ws * berev + wn;
        const float den = bcmt + bgl + ws + wd;
        v2 = num / den;
    }

    if (u == 0)
        out[b] = 1.0f / (1.0f + __builtin_amdgcn_exp2f(-v2 * LOG2E));
}

extern "C" void kernel_launch(void* const* d_in, const int* in_sizes, int n_in,
                              void* d_out, int out_size, void* d_ws, size_t ws_size,
                              hipStream_t stream) {
    const float* x       = (const float*)d_in[0];
    const float* a_iw    = (const float*)d_in[1];
    const float* a_ib    = (const float*)d_in[2];
    const float* a_smu   = (const float*)d_in[3];
    const float* a_ssig  = (const float*)d_in[4];
    const float* a_sW    = (const float*)d_in[5];
    const float* a_serev = (const float*)d_in[6];
    const float* a_mu    = (const float*)d_in[7];
    const float* a_sig   = (const float*)d_in[8];
    const float* a_W     = (const float*)d_in[9];
    const float* a_erev  = (const float*)d_in[10];
    const float* a_gleak = (const float*)d_in[11];
    const float* a_vleak = (const float*)d_in[12];
    const float* a_cm    = (const float*)d_in[13];
    const float* b_iw    = (const float*)d_in[14];
    const float* b_ib    = (const float*)d_in[15];
    const float* b_smu   = (const float*)d_in[16];
    const float* b_ssig  = (const float*)d_in[17];
    const float* b_sW    = (const float*)d_in[18];
    const float* b_serev = (const float*)d_in[19];
    const float* b_mu    = (const float*)d_in[20];
    const float* b_sig   = (const float*)d_in[21];
    const float* b_W     = (const float*)d_in[22];
    const float* b_erev  = (const float*)d_in[23];
    const float* b_gleak = (const float*)d_in[24];
    const float* b_vleak = (const float*)d_in[25];
    const float* b_cm    = (const float*)d_in[26];
    float* out = (float*)d_out;

    float4* Ppk  = (float4*)d_ws;                                // 5.24 MB
    float2* part = (float2*)(Ppk + (size_t)IN1 * NU);            // 8.39 MB
    float2* Sarr = part + (size_t)SPLITS * BATCH * NU;           // 16 KB

    ltc_pack<<<(IN1 * NU) / 256, 256, 0, stream>>>(
        a_iw, a_ib, a_smu, a_ssig, a_sW, a_serev, Ppk);

    dim3 g1(BATCH / BBLK, SPLITS);
    ltc_sensory_partial<<<g1, 256, 0, stream>>>(x, Ppk, part);

    ltc_reduce<<<BATCH, 256, 0, stream>>>(part, SPLITS, Sarr);

    ltc_unfold<<<BATCH / 8, 256, 0, stream>>>(
        Sarr,
        a_mu, a_sig, a_W, a_erev, a_gleak, a_vleak, a_cm,
        b_iw, b_ib, b_smu, b_ssig, b_sW, b_serev,
        b_mu, b_sig, b_W, b_erev, b_gleak, b_vleak, b_cm,
        out);
}